// Round 10
// baseline (733.335 us; speedup 1.0000x reference)
//
#include <hip/hip_runtime.h>

using half8  = __attribute__((ext_vector_type(8))) _Float16;
using half4v = __attribute__((ext_vector_type(4))) _Float16;
using f32x4  = __attribute__((ext_vector_type(4))) float;

#define MFMA16(a,b,c) __builtin_amdgcn_mfma_f32_16x16x32_f16((a),(b),(c),0,0,0)
#define LOG2E 1.4426950408889634f
#define KTC  -2.8853900817779268f   /* -2*log2(e): tanh(c) = 2/(1+2^(c*KTC)) - 1 */

__device__ __forceinline__ float sigp_(float zp){           // sigmoid, zp pre-scaled by log2e
  return __builtin_amdgcn_rcpf(1.0f + exp2f(-zp));
}
__device__ __forceinline__ float tanhp_(float zp){          // tanh, zp pre-scaled by log2e
  return fmaf(2.0f, __builtin_amdgcn_rcpf(1.0f + exp2f(-2.0f*zp)), -1.0f);
}
__device__ __forceinline__ float tanhn_(float x){           // tanh, natural units
  return fmaf(2.0f, __builtin_amdgcn_rcpf(1.0f + exp2f(x*KTC)), -1.0f);
}

// ---------------- K0: weight transposes / fp16 packing ----------------
// wkt, wrtb carry a baked log2(e) factor so gates use raw exp2.
// wrtb linear: [4 jt][256 r][256 k], r = 64*gate + i  <-> g = 256*gate + 64*jt + i
__global__ void k0_prep(const float* __restrict__ Wk, const float* __restrict__ Wr,
                        const float* __restrict__ Wd, _Float16* __restrict__ wkt,
                        _Float16* __restrict__ wrtb, _Float16* __restrict__ wdt)
{
  int i = blockIdx.x * 256 + threadIdx.x;
  if (i < 1024*320) {
    int g = i / 320, k = i - g*320;
    wkt[i] = (_Float16)((k < 300) ? Wk[k*1024 + g]*LOG2E : 0.0f);
  }
  if (i < 4*256*256) {
    int jt = i >> 16, r = (i >> 8) & 255, k = i & 255;
    int g = ((r >> 6) << 8) + (jt << 6) + (r & 63);
    wrtb[i] = (_Float16)(Wr[k*1024 + g]*LOG2E);
  }
  if (i < 256*512) {
    int d = i >> 9, k = i & 511;
    wdt[i] = (_Float16)Wd[k*256 + d];
  }
}

// ---------------- K1: embW = (emb @ Wk + b)*log2e -> embw[v][1024] ----------------
__global__ __launch_bounds__(512, 2) void k1_embw(
    const float* __restrict__ emb, const float* __restrict__ bias,
    const _Float16* __restrict__ wkt, _Float16* __restrict__ embw)
{
  __shared__ _Float16 a_s[1024][40];
  __shared__ _Float16 e_s[64][40];
  const int tid = threadIdx.x;
  const int wv = tid >> 6, ln = tid & 63, l16 = ln & 15, lq = ln >> 4;
  const int v0 = blockIdx.x * 64;

  f32x4 acc[8][4];
  #pragma unroll
  for (int ml=0;ml<8;++ml)
    #pragma unroll
    for (int nt=0;nt<4;++nt){ f32x4 z0; z0[0]=0.f;z0[1]=0.f;z0[2]=0.f;z0[3]=0.f; acc[ml][nt]=z0; }

  const int evv = tid >> 2;
  const int ekq = tid & 3;

  for (int c = 0; c < 10; ++c) {
    {
      const uint4* sp  = (const uint4*)(wkt + (size_t)(2*tid)*320 + 32*c);
      uint4 r0=sp[0], r1=sp[1], r2=sp[2], r3=sp[3];
      const uint4* sp2 = (const uint4*)(wkt + (size_t)(2*tid+1)*320 + 32*c);
      uint4 r4=sp2[0], r5=sp2[1], r6=sp2[2], r7=sp2[3];
      uint4* dq  = (uint4*)&a_s[2*tid][0];
      dq[0]=r0; dq[1]=r1; dq[2]=r2; dq[3]=r3;
      uint4* dq2 = (uint4*)&a_s[2*tid+1][0];
      dq2[0]=r4; dq2[1]=r5; dq2[2]=r6; dq2[3]=r7;
    }
    if (tid < 256) {
      int vsrc = v0 + evv; if (vsrc > 19999) vsrc = 19999;
      float f0,f1,f2,f3,f4,f5,f6,f7;
      if (c < 9) {
        const float4* sp = (const float4*)(emb + (size_t)vsrc*300 + 32*c + 8*ekq);
        float4 fa = sp[0], fb = sp[1];
        f0=fa.x; f1=fa.y; f2=fa.z; f3=fa.w; f4=fb.x; f5=fb.y; f6=fb.z; f7=fb.w;
      } else {
        const float* sp = emb + (size_t)vsrc*300;
        int k0 = 288 + 8*ekq;
        f0 = (k0+0<300)? sp[k0+0] : 0.f;  f1 = (k0+1<300)? sp[k0+1] : 0.f;
        f2 = (k0+2<300)? sp[k0+2] : 0.f;  f3 = (k0+3<300)? sp[k0+3] : 0.f;
        f4 = (k0+4<300)? sp[k0+4] : 0.f;  f5 = (k0+5<300)? sp[k0+5] : 0.f;
        f6 = (k0+6<300)? sp[k0+6] : 0.f;  f7 = (k0+7<300)? sp[k0+7] : 0.f;
      }
      half8 hv;
      hv[0]=(_Float16)f0; hv[1]=(_Float16)f1; hv[2]=(_Float16)f2; hv[3]=(_Float16)f3;
      hv[4]=(_Float16)f4; hv[5]=(_Float16)f5; hv[6]=(_Float16)f6; hv[7]=(_Float16)f7;
      *(half8*)&e_s[evv][8*ekq] = hv;
    }
    __syncthreads();
    half8 bf[4];
    #pragma unroll
    for (int nt=0;nt<4;++nt) bf[nt] = *(const half8*)&e_s[16*nt + l16][8*lq];
    #pragma unroll
    for (int ml=0;ml<8;++ml) {
      half8 af = *(const half8*)&a_s[16*(8*wv+ml) + l16][8*lq];
      #pragma unroll
      for (int nt=0;nt<4;++nt) acc[ml][nt] = MFMA16(af, bf[nt], acc[ml][nt]);
    }
    __syncthreads();
  }
  #pragma unroll
  for (int ml=0;ml<8;++ml) {
    int g0 = 16*(8*wv+ml) + 4*lq;
    float4 bv = *(const float4*)&bias[g0];
    float bvr[4] = {bv.x*LOG2E, bv.y*LOG2E, bv.z*LOG2E, bv.w*LOG2E};
    int jt = (g0 >> 6) & 3;
    int c0 = ((g0 >> 8) << 6) + (g0 & 63);
    #pragma unroll
    for (int nt=0;nt<4;++nt) {
      int v = v0 + 16*nt + l16;
      if (v < 20000) {
        half4v hv;
        hv[0]=(_Float16)(acc[ml][nt][0]+bvr[0]);
        hv[1]=(_Float16)(acc[ml][nt][1]+bvr[1]);
        hv[2]=(_Float16)(acc[ml][nt][2]+bvr[2]);
        hv[3]=(_Float16)(acc[ml][nt][3]+bvr[3]);
        *(half4v*)&embw[(size_t)v*1024 + 256*jt + c0] = hv;
      }
    }
  }
}

// ---------------- K2: bi-LSTM recurrence, 1 block = (card, direction) ----------------
// R10 change (vs R9): jt and kq are REAL loops (#pragma unroll 1) and aR is a single
// just-in-time buffer. R6-R9's persistent 110-174MB scratch spill came from live-range
// inflation: the fully-unrolled jt*kq body (one huge scheduling region per step) let
// the scheduler hoist ~100 loads and rename the double-buffers into many copies ->
// pressure over the cap -> spill -> scratch-throttled occupancy. Small loop bodies
// bound the window: live set = eR 24 + aR 32 + acc 48 + addr ~30, far under cap.
// c stays in LDS (dynamic-jt register indexing would itself be scratch, rule #20).

#define NEXT_IDXC(T) do { int tt_ = dtt0 + dsgn*(T); \
    _Pragma("unroll") for (int nt=0;nt<3;++nt) \
      idxc[nt] = x[xb + pA[nt]*12 + tt_]; \
  } while(0)

#define ISSUE_E(JT) do { \
    _Pragma("unroll") for (int nt=0;nt<3;++nt) { \
      const _Float16* ep = embw + (size_t)idxc[nt]*1024 + 256*(JT) + ebase; \
      _Pragma("unroll") for (int g=0;g<4;++g) eR[g][nt] = *(const half4v*)(ep + 64*g); \
    } } while(0)

#define ACC_FROM_E() do { \
    _Pragma("unroll") for (int g=0;g<4;++g) \
      _Pragma("unroll") for (int nt=0;nt<3;++nt) { \
        f32x4 a0; a0[0]=(float)eR[g][nt][0]; a0[1]=(float)eR[g][nt][1]; \
        a0[2]=(float)eR[g][nt][2]; a0[3]=(float)eR[g][nt][3]; acc[g][nt]=a0; \
      } } while(0)

#define ISSUE_A(JT,KQ) do { \
    const _Float16* ap = wrtb + abase + 65536*(JT) + 64*(KQ); \
    _Pragma("unroll") for (int g=0;g<4;++g) { \
      aR[2*g+0] = *(const half8*)(ap + 16384*g); \
      aR[2*g+1] = *(const half8*)(ap + 16384*g + 32); \
    } } while(0)

#define MFMAQ(KQ) do { \
    _Pragma("unroll") for (int kk2=0;kk2<2;++kk2) { \
      half8 bF[3]; \
      _Pragma("unroll") for (int nt=0;nt<3;++nt) \
        bF[nt] = *(const half8*)(hc + bbase[nt] + ((64*(KQ)+32*kk2+8*lq) ^ bswz[nt])); \
      _Pragma("unroll") for (int g=0;g<4;++g) \
        _Pragma("unroll") for (int nt=0;nt<3;++nt) \
          acc[g][nt] = MFMA16(aR[2*g+kk2], bF[nt], acc[g][nt]); \
    } } while(0)

#define GATES(JT) do { \
    const int ccol_ = 64*(JT) + chb; \
    _Pragma("unroll") for (int nt=0;nt<3;++nt) { \
      f32x4 cv = *(const f32x4*)&c_s[16*nt + l16][ccol_]; \
      f32x4 cn_; half4v hv; \
      _Pragma("unroll") for (int r=0;r<4;++r) { \
        float zi=acc[0][nt][r], zf=acc[1][nt][r], zg=acc[2][nt][r], zo=acc[3][nt][r]; \
        float cn = fmaf(sigp_(zf), cv[r], sigp_(zi)*tanhp_(zg)); \
        cn_[r]=cn; hv[r]=(_Float16)(sigp_(zo)*tanhn_(cn)); \
      } \
      *(f32x4*)&c_s[16*nt + l16][ccol_] = cn_; \
      *(half4v*)(hn + bbase[nt] + ((64*(JT)+16*hq+4*lq) ^ bswz[nt])) = hv; \
    } } while(0)

#define GATES0(JT) do { \
    const int ccol_ = 64*(JT) + chb; \
    _Pragma("unroll") for (int nt=0;nt<3;++nt) { \
      f32x4 cn_; half4v hv; \
      _Pragma("unroll") for (int r=0;r<4;++r) { \
        float zi=acc[0][nt][r], zg=acc[2][nt][r], zo=acc[3][nt][r]; \
        float cn = sigp_(zi)*tanhp_(zg); \
        cn_[r]=cn; hv[r]=(_Float16)(sigp_(zo)*tanhn_(cn)); \
      } \
      *(f32x4*)&c_s[16*nt + l16][ccol_] = cn_; \
      *(half4v*)(hn + bbase[nt] + ((64*(JT)+16*hq+4*lq) ^ bswz[nt])) = hv; \
    } } while(0)

__global__ __launch_bounds__(256, 1) void k2_rnn(
    const int* __restrict__ x, const _Float16* __restrict__ embw,
    const _Float16* __restrict__ wrtb, _Float16* __restrict__ hstate)
{
  __shared__ _Float16 h_s[2][48][256];   // 48 KB
  __shared__ float    c_s[48][260];      // 49.9 KB cell state (pad 260: 16B row stagger)

  const int bid = blockIdx.x;
  const int b   = bid & 255;             // card
  const int dir = bid >> 8;              // 0 = fw, 1 = bw (block-uniform)
  const int tid = threadIdx.x;
  const int wv  = tid >> 6;
  const int ln  = tid & 63;
  const int l16 = ln & 15;
  const int lq  = ln >> 4;
  const int hq  = wv;                    // 16-col subtile in each 64-col gate chunk

  const int dtt0 = dir ? 11 : 0;
  const int dsgn = dir ? -1 : 1;

  int pA[3], bbase[3], bswz[3];
  #pragma unroll
  for (int nt=0;nt<3;++nt) {
    int s = 16*nt + l16;                 // seq row 0..47 (40..47 dup path 39)
    pA[nt] = (s < 40) ? s : 39;
    bbase[nt] = s*256; bswz[nt] = (s&7)<<3;
  }
  const int xb = b*480;
  const int ebase = 16*hq + 4*lq;
  const int chb = 16*hq + 4*lq;          // c column base within a 64-col jt chunk
  const size_t abase = (size_t)(16*hq + l16)*256 + 8*lq;

  half4v eR[4][3];
  half8  aR[8];
  f32x4  acc[4][3];
  int idxc[3];

  NEXT_IDXC(0);
  ISSUE_E(0);

  // ---- t = 0: z = xg (h=0, no MFMA; c starts at 0 via GATES0) ----
  {
    _Float16* hn = &h_s[1][0][0];
    #pragma unroll 1
    for (int jt = 0; jt < 4; ++jt) {
      ACC_FROM_E();
      if (jt < 3) { ISSUE_E(jt+1); }
      else        { NEXT_IDXC(1); ISSUE_E(0); }
      GATES0(jt);
    }
  }

  // ---- t = 1..11: 16 slices/step, ONE barrier/step; small loop bodies ----
  #pragma unroll 1
  for (int t = 1; t < 12; ++t) {
    __syncthreads();                     // h[t&1] committed by all waves
    const _Float16* hc = &h_s[t&1][0][0];
    _Float16*       hn = &h_s[(t+1)&1][0][0];
    const bool last = (t == 11);
    #pragma unroll 1
    for (int jt = 0; jt < 4; ++jt) {
      ACC_FROM_E();
      if (jt < 3)      { ISSUE_E(jt+1); }
      else if (!last)  { NEXT_IDXC(t+1); ISSUE_E(0); }
      #pragma unroll 1
      for (int kq = 0; kq < 4; ++kq) {
        ISSUE_A(jt, kq);                 // single-buffer, just-in-time (L2-resident)
        MFMAQ(kq);
      }
      GATES(jt);
    }
  }
  __syncthreads();                       // final state (h_s[0]) committed

  // ---- export final h (unswizzled) to hstate[b][dir][40][256] ----
  #pragma unroll
  for (int pass = 0; pass < 5; ++pass) {
    int row = 8*pass + (tid >> 5);
    int c0  = (tid & 31) * 8;
    half8 v = *(const half8*)&h_s[0][row][c0 ^ ((row & 7) << 3)];
    *(half8*)&hstate[(((size_t)b*2 + dir)*40 + row)*256 + c0] = v;
  }
}

// ---------------- K3: dense + attention head, 1 block = 1 card ----------------
__global__ __launch_bounds__(256) void k3_head(
    const float* __restrict__ bd, const float* __restrict__ att,
    const _Float16* __restrict__ hstate, const _Float16* __restrict__ wdt,
    float* __restrict__ out)
{
  __shared__ _Float16 d_s[256][56];
  __shared__ float att_s[256];
  __shared__ float sc_s[40];
  __shared__ float wgt[40];

  const int b   = blockIdx.x;
  const int tid = threadIdx.x;
  const int wv  = tid >> 6;
  const int ln  = tid & 63;
  const int l16 = ln & 15;
  const int lq  = ln >> 4;

  att_s[tid] = att[tid];

  int pD2[3];
  #pragma unroll
  for (int nt=0;nt<3;++nt){ int p = 16*nt + l16; pD2[nt] = (p < 40) ? p : 39; }
  const _Float16* hb = hstate + (size_t)b*2*40*256;

  f32x4 dacc[4][3];
  #pragma unroll
  for (int ml=0;ml<4;++ml)
    #pragma unroll
    for (int nt=0;nt<3;++nt){ f32x4 z0; z0[0]=0.f;z0[1]=0.f;z0[2]=0.f;z0[3]=0.f; dacc[ml][nt]=z0; }

  #pragma unroll
  for (int kq = 0; kq < 8; ++kq) {        // k slices of 64: 0..3 fw state, 4..7 bw state
    half8 adA[4], adB[4];
    #pragma unroll
    for (int ml=0;ml<4;++ml) {
      const _Float16* wp = wdt + (size_t)(16*(4*wv+ml)+l16)*512 + 64*kq + 8*lq;
      adA[ml] = *(const half8*)(wp);
      adB[ml] = *(const half8*)(wp + 32);
    }
    #pragma unroll
    for (int kk2=0;kk2<2;++kk2) {
      half8 bD[3];
      #pragma unroll
      for (int nt=0;nt<3;++nt)
        bD[nt] = *(const half8*)(hb + ((size_t)(kq>>2)*40 + pD2[nt])*256
                                    + 64*(kq&3) + 32*kk2 + 8*lq);
      #pragma unroll
      for (int ml=0;ml<4;++ml) {
        half8 a0 = kk2 ? adB[ml] : adA[ml];
        #pragma unroll
        for (int nt=0;nt<3;++nt) dacc[ml][nt] = MFMA16(a0, bD[nt], dacc[ml][nt]);
      }
    }
  }
  #pragma unroll
  for (int ml = 0; ml < 4; ++ml) {
    int d0 = 16*(4*wv+ml) + 4*lq;
    float4 bv = *(const float4*)&bd[d0];
    float bvr[4] = {bv.x, bv.y, bv.z, bv.w};
    #pragma unroll
    for (int nt = 0; nt < 3; ++nt) {
      int p = 16*nt + l16;
      #pragma unroll
      for (int r = 0; r < 4; ++r) {
        float val = tanhn_(dacc[ml][nt][r] + bvr[r]);
        d_s[d0 + r][p] = (_Float16)val;
      }
    }
  }
  __syncthreads();
  // ---------- attention: 10 path-scores per wave, softmax, weighted sum ----------
  #pragma unroll
  for (int q = 0; q < 10; ++q) {
    int pp = 10*wv + q;
    float s = 0.0f;
    #pragma unroll
    for (int j = 0; j < 4; ++j) {
      int d = 64*j + ln;
      s += (float)d_s[d][pp] * att_s[d];
    }
    #pragma unroll
    for (int off = 32; off > 0; off >>= 1) s += __shfl_xor(s, off);
    if (ln == 0) sc_s[pp] = s;
  }
  __syncthreads();
  if (wv == 0) {
    float sc = (ln < 40) ? sc_s[ln] : -1e30f;
    float m = sc;
    #pragma unroll
    for (int off = 32; off > 0; off >>= 1) m = fmaxf(m, __shfl_xor(m, off));
    float e = __expf(sc - m);
    float se = e;
    #pragma unroll
    for (int off = 32; off > 0; off >>= 1) se += __shfl_xor(se, off);
    if (ln < 40) wgt[ln] = e / se;
  }
  __syncthreads();
  {
    float o = 0.0f;
    #pragma unroll 8
    for (int p = 0; p < 40; ++p) o += wgt[p] * (float)d_s[tid][p];
    out[b*256 + tid] = o;
  }
}

extern "C" void kernel_launch(void* const* d_in, const int* in_sizes, int n_in,
                              void* d_out, int out_size, void* d_ws, size_t ws_size,
                              hipStream_t stream)
{
  (void)in_sizes; (void)n_in; (void)out_size;
  const int*   x   = (const int*)  d_in[0];
  const float* emb = (const float*)d_in[1];
  const float* Wk  = (const float*)d_in[2];
  const float* Wr  = (const float*)d_in[3];
  const float* bi  = (const float*)d_in[4];
  const float* Wd  = (const float*)d_in[5];
  const float* bd  = (const float*)d_in[6];
  const float* att = (const float*)d_in[7];
  float* out = (float*)d_out;

  if (ws_size < 52887552u) return;   // need 52.9 MB scratch
  char* ws = (char*)d_ws;
  _Float16* embw   = (_Float16*)(ws + 0);          // [20000][1024] fp16 = 40,960,000 B
  _Float16* wrtb   = (_Float16*)(ws + 40960000);   // [4][256][256] fp16 =    524,288 B
  _Float16* wkt    = (_Float16*)(ws + 41484288);   // [1024][320]   fp16 =    655,360 B
  _Float16* wdt    = (_Float16*)(ws + 42139648);   // [256][512]    fp16 =    262,144 B
  _Float16* hstate = (_Float16*)(ws + 42401792);   // [256][2][40][256] fp16 = 10,485,760 B

  k0_prep<<<dim3(1280), dim3(256), 0, stream>>>(Wk, Wr, Wd, wkt, wrtb, wdt);
  k1_embw<<<dim3(313), dim3(512), 0, stream>>>(emb, bi, wkt, embw);
  k2_rnn <<<dim3(512), dim3(256), 0, stream>>>(x, embw, wrtb, hstate);
  k3_head<<<dim3(256), dim3(256), 0, stream>>>(bd, att, hstate, wdt, out);
}

// Round 11
// 625.380 us; speedup vs baseline: 1.1726x; 1.1726x over previous
//
#include <hip/hip_runtime.h>

using half8  = __attribute__((ext_vector_type(8))) _Float16;
using half4v = __attribute__((ext_vector_type(4))) _Float16;
using f32x4  = __attribute__((ext_vector_type(4))) float;

#define MFMA16(a,b,c) __builtin_amdgcn_mfma_f32_16x16x32_f16((a),(b),(c),0,0,0)
#define LOG2E 1.4426950408889634f
#define KTC  -2.8853900817779268f   /* -2*log2(e): tanh(c) = 2/(1+2^(c*KTC)) - 1 */

__device__ __forceinline__ float sigp_(float zp){           // sigmoid, zp pre-scaled by log2e
  return __builtin_amdgcn_rcpf(1.0f + exp2f(-zp));
}
__device__ __forceinline__ float tanhp_(float zp){          // tanh, zp pre-scaled by log2e
  return fmaf(2.0f, __builtin_amdgcn_rcpf(1.0f + exp2f(-2.0f*zp)), -1.0f);
}
__device__ __forceinline__ float tanhn_(float x){           // tanh, natural units
  return fmaf(2.0f, __builtin_amdgcn_rcpf(1.0f + exp2f(x*KTC)), -1.0f);
}

// ---------------- K0: weight transposes / fp16 packing ----------------
// wkt, wrtb carry a baked log2(e) factor so gates use raw exp2.
// wrtb linear: [4 jt][256 r][256 k], r = 64*gate + i  <-> g = 256*gate + 64*jt + i
__global__ void k0_prep(const float* __restrict__ Wk, const float* __restrict__ Wr,
                        const float* __restrict__ Wd, _Float16* __restrict__ wkt,
                        _Float16* __restrict__ wrtb, _Float16* __restrict__ wdt)
{
  int i = blockIdx.x * 256 + threadIdx.x;
  if (i < 1024*320) {
    int g = i / 320, k = i - g*320;
    wkt[i] = (_Float16)((k < 300) ? Wk[k*1024 + g]*LOG2E : 0.0f);
  }
  if (i < 4*256*256) {
    int jt = i >> 16, r = (i >> 8) & 255, k = i & 255;
    int g = ((r >> 6) << 8) + (jt << 6) + (r & 63);
    wrtb[i] = (_Float16)(Wr[k*1024 + g]*LOG2E);
  }
  if (i < 256*512) {
    int d = i >> 9, k = i & 511;
    wdt[i] = (_Float16)Wd[k*256 + d];
  }
}

// ---------------- K1: embW = (emb @ Wk + b)*log2e -> embw[v][1024] ----------------
__global__ __launch_bounds__(512, 2) void k1_embw(
    const float* __restrict__ emb, const float* __restrict__ bias,
    const _Float16* __restrict__ wkt, _Float16* __restrict__ embw)
{
  __shared__ _Float16 a_s[1024][40];
  __shared__ _Float16 e_s[64][40];
  const int tid = threadIdx.x;
  const int wv = tid >> 6, ln = tid & 63, l16 = ln & 15, lq = ln >> 4;
  const int v0 = blockIdx.x * 64;

  f32x4 acc[8][4];
  #pragma unroll
  for (int ml=0;ml<8;++ml)
    #pragma unroll
    for (int nt=0;nt<4;++nt){ f32x4 z0; z0[0]=0.f;z0[1]=0.f;z0[2]=0.f;z0[3]=0.f; acc[ml][nt]=z0; }

  const int evv = tid >> 2;
  const int ekq = tid & 3;

  for (int c = 0; c < 10; ++c) {
    {
      const uint4* sp  = (const uint4*)(wkt + (size_t)(2*tid)*320 + 32*c);
      uint4 r0=sp[0], r1=sp[1], r2=sp[2], r3=sp[3];
      const uint4* sp2 = (const uint4*)(wkt + (size_t)(2*tid+1)*320 + 32*c);
      uint4 r4=sp2[0], r5=sp2[1], r6=sp2[2], r7=sp2[3];
      uint4* dq  = (uint4*)&a_s[2*tid][0];
      dq[0]=r0; dq[1]=r1; dq[2]=r2; dq[3]=r3;
      uint4* dq2 = (uint4*)&a_s[2*tid+1][0];
      dq2[0]=r4; dq2[1]=r5; dq2[2]=r6; dq2[3]=r7;
    }
    if (tid < 256) {
      int vsrc = v0 + evv; if (vsrc > 19999) vsrc = 19999;
      float f0,f1,f2,f3,f4,f5,f6,f7;
      if (c < 9) {
        const float4* sp = (const float4*)(emb + (size_t)vsrc*300 + 32*c + 8*ekq);
        float4 fa = sp[0], fb = sp[1];
        f0=fa.x; f1=fa.y; f2=fa.z; f3=fa.w; f4=fb.x; f5=fb.y; f6=fb.z; f7=fb.w;
      } else {
        const float* sp = emb + (size_t)vsrc*300;
        int k0 = 288 + 8*ekq;
        f0 = (k0+0<300)? sp[k0+0] : 0.f;  f1 = (k0+1<300)? sp[k0+1] : 0.f;
        f2 = (k0+2<300)? sp[k0+2] : 0.f;  f3 = (k0+3<300)? sp[k0+3] : 0.f;
        f4 = (k0+4<300)? sp[k0+4] : 0.f;  f5 = (k0+5<300)? sp[k0+5] : 0.f;
        f6 = (k0+6<300)? sp[k0+6] : 0.f;  f7 = (k0+7<300)? sp[k0+7] : 0.f;
      }
      half8 hv;
      hv[0]=(_Float16)f0; hv[1]=(_Float16)f1; hv[2]=(_Float16)f2; hv[3]=(_Float16)f3;
      hv[4]=(_Float16)f4; hv[5]=(_Float16)f5; hv[6]=(_Float16)f6; hv[7]=(_Float16)f7;
      *(half8*)&e_s[evv][8*ekq] = hv;
    }
    __syncthreads();
    half8 bf[4];
    #pragma unroll
    for (int nt=0;nt<4;++nt) bf[nt] = *(const half8*)&e_s[16*nt + l16][8*lq];
    #pragma unroll
    for (int ml=0;ml<8;++ml) {
      half8 af = *(const half8*)&a_s[16*(8*wv+ml) + l16][8*lq];
      #pragma unroll
      for (int nt=0;nt<4;++nt) acc[ml][nt] = MFMA16(af, bf[nt], acc[ml][nt]);
    }
    __syncthreads();
  }
  #pragma unroll
  for (int ml=0;ml<8;++ml) {
    int g0 = 16*(8*wv+ml) + 4*lq;
    float4 bv = *(const float4*)&bias[g0];
    float bvr[4] = {bv.x*LOG2E, bv.y*LOG2E, bv.z*LOG2E, bv.w*LOG2E};
    int jt = (g0 >> 6) & 3;
    int c0 = ((g0 >> 8) << 6) + (g0 & 63);
    #pragma unroll
    for (int nt=0;nt<4;++nt) {
      int v = v0 + 16*nt + l16;
      if (v < 20000) {
        half4v hv;
        hv[0]=(_Float16)(acc[ml][nt][0]+bvr[0]);
        hv[1]=(_Float16)(acc[ml][nt][1]+bvr[1]);
        hv[2]=(_Float16)(acc[ml][nt][2]+bvr[2]);
        hv[3]=(_Float16)(acc[ml][nt][3]+bvr[3]);
        *(half4v*)&embw[(size_t)v*1024 + 256*jt + c0] = hv;
      }
    }
  }
}

// ---------------- K2: bi-LSTM recurrence, 1 block = (card, direction) ----------------
// R11 change (vs R10): restore ILP inside the (bounded) jt body via a two-slice
// register rotation with STATIC buffer names (aRa/aRb, rule-#20 safe). R10 was
// spill-free (WRITE 10.2MB, VGPR 132) but JIT single-buffered A-loads exposed a full
// L2 latency on every one of the 16 slices at 1 wave/SIMD -> regression. Rotation:
// issue(a,kq0) issue(b,kq1) | mfma(a) issue(a,kq2) | mfma(b) issue(b,kq3) | mfma(a)
// | mfma(b) -> only the first slice of each jt pays the latency. eR gathers for jt+1
// issue before the MFMA phase (~500cyc hiding). Live set ~160 regs, still < cap.

#define NEXT_IDXC(T) do { int tt_ = dtt0 + dsgn*(T); \
    _Pragma("unroll") for (int nt=0;nt<3;++nt) \
      idxc[nt] = x[xb + pA[nt]*12 + tt_]; \
  } while(0)

#define ISSUE_E(JT) do { \
    _Pragma("unroll") for (int nt=0;nt<3;++nt) { \
      const _Float16* ep = embw + (size_t)idxc[nt]*1024 + 256*(JT) + ebase; \
      _Pragma("unroll") for (int g=0;g<4;++g) eR[g][nt] = *(const half4v*)(ep + 64*g); \
    } } while(0)

#define ACC_FROM_E() do { \
    _Pragma("unroll") for (int g=0;g<4;++g) \
      _Pragma("unroll") for (int nt=0;nt<3;++nt) { \
        f32x4 a0; a0[0]=(float)eR[g][nt][0]; a0[1]=(float)eR[g][nt][1]; \
        a0[2]=(float)eR[g][nt][2]; a0[3]=(float)eR[g][nt][3]; acc[g][nt]=a0; \
      } } while(0)

#define ISSUE_A(BUF,JT,KQ) do { \
    const _Float16* ap = wrtb + abase + 65536*(JT) + 64*(KQ); \
    _Pragma("unroll") for (int g=0;g<4;++g) { \
      BUF[2*g+0] = *(const half8*)(ap + 16384*g); \
      BUF[2*g+1] = *(const half8*)(ap + 16384*g + 32); \
    } } while(0)

#define MFMAQ(BUF,KQ) do { \
    _Pragma("unroll") for (int kk2=0;kk2<2;++kk2) { \
      half8 bF[3]; \
      _Pragma("unroll") for (int nt=0;nt<3;++nt) \
        bF[nt] = *(const half8*)(hc + bbase[nt] + ((64*(KQ)+32*kk2+8*lq) ^ bswz[nt])); \
      _Pragma("unroll") for (int g=0;g<4;++g) \
        _Pragma("unroll") for (int nt=0;nt<3;++nt) \
          acc[g][nt] = MFMA16(BUF[2*g+kk2], bF[nt], acc[g][nt]); \
    } } while(0)

#define GATES(JT) do { \
    const int ccol_ = 64*(JT) + chb; \
    _Pragma("unroll") for (int nt=0;nt<3;++nt) { \
      f32x4 cv = *(const f32x4*)&c_s[16*nt + l16][ccol_]; \
      f32x4 cn_; half4v hv; \
      _Pragma("unroll") for (int r=0;r<4;++r) { \
        float zi=acc[0][nt][r], zf=acc[1][nt][r], zg=acc[2][nt][r], zo=acc[3][nt][r]; \
        float cn = fmaf(sigp_(zf), cv[r], sigp_(zi)*tanhp_(zg)); \
        cn_[r]=cn; hv[r]=(_Float16)(sigp_(zo)*tanhn_(cn)); \
      } \
      *(f32x4*)&c_s[16*nt + l16][ccol_] = cn_; \
      *(half4v*)(hn + bbase[nt] + ((64*(JT)+16*hq+4*lq) ^ bswz[nt])) = hv; \
    } } while(0)

#define GATES0(JT) do { \
    const int ccol_ = 64*(JT) + chb; \
    _Pragma("unroll") for (int nt=0;nt<3;++nt) { \
      f32x4 cn_; half4v hv; \
      _Pragma("unroll") for (int r=0;r<4;++r) { \
        float zi=acc[0][nt][r], zg=acc[2][nt][r], zo=acc[3][nt][r]; \
        float cn = sigp_(zi)*tanhp_(zg); \
        cn_[r]=cn; hv[r]=(_Float16)(sigp_(zo)*tanhn_(cn)); \
      } \
      *(f32x4*)&c_s[16*nt + l16][ccol_] = cn_; \
      *(half4v*)(hn + bbase[nt] + ((64*(JT)+16*hq+4*lq) ^ bswz[nt])) = hv; \
    } } while(0)

__global__ __launch_bounds__(256, 1) void k2_rnn(
    const int* __restrict__ x, const _Float16* __restrict__ embw,
    const _Float16* __restrict__ wrtb, _Float16* __restrict__ hstate)
{
  __shared__ _Float16 h_s[2][48][256];   // 48 KB
  __shared__ float    c_s[48][260];      // 49.9 KB cell state (pad 260: 16B row stagger)

  const int bid = blockIdx.x;
  const int b   = bid & 255;             // card
  const int dir = bid >> 8;              // 0 = fw, 1 = bw (block-uniform)
  const int tid = threadIdx.x;
  const int wv  = tid >> 6;
  const int ln  = tid & 63;
  const int l16 = ln & 15;
  const int lq  = ln >> 4;
  const int hq  = wv;                    // 16-col subtile in each 64-col gate chunk

  const int dtt0 = dir ? 11 : 0;
  const int dsgn = dir ? -1 : 1;

  int pA[3], bbase[3], bswz[3];
  #pragma unroll
  for (int nt=0;nt<3;++nt) {
    int s = 16*nt + l16;                 // seq row 0..47 (40..47 dup path 39)
    pA[nt] = (s < 40) ? s : 39;
    bbase[nt] = s*256; bswz[nt] = (s&7)<<3;
  }
  const int xb = b*480;
  const int ebase = 16*hq + 4*lq;
  const int chb = 16*hq + 4*lq;          // c column base within a 64-col jt chunk
  const size_t abase = (size_t)(16*hq + l16)*256 + 8*lq;

  half4v eR[4][3];
  half8  aRa[8], aRb[8];
  f32x4  acc[4][3];
  int idxc[3];

  NEXT_IDXC(0);
  ISSUE_E(0);

  // ---- t = 0: z = xg (h=0, no MFMA; c starts at 0 via GATES0) ----
  {
    _Float16* hn = &h_s[1][0][0];
    #pragma unroll 1
    for (int jt = 0; jt < 4; ++jt) {
      ACC_FROM_E();
      if (jt < 3) { ISSUE_E(jt+1); }
      else        { NEXT_IDXC(1); ISSUE_E(0); }
      GATES0(jt);
    }
  }

  // ---- t = 1..11: 4 jt chunks/step, 2-slice A rotation inside each ----
  #pragma unroll 1
  for (int t = 1; t < 12; ++t) {
    __syncthreads();                     // h[t&1] committed by all waves
    const _Float16* hc = &h_s[t&1][0][0];
    _Float16*       hn = &h_s[(t+1)&1][0][0];
    const bool last = (t == 11);
    #pragma unroll 1
    for (int jt = 0; jt < 4; ++jt) {
      ISSUE_A(aRa, jt, 0);               // slices 0,1 in flight
      ISSUE_A(aRb, jt, 1);
      ACC_FROM_E();
      if (jt < 3)      { ISSUE_E(jt+1); }
      else if (!last)  { NEXT_IDXC(t+1); ISSUE_E(0); }
      MFMAQ(aRa, 0);
      ISSUE_A(aRa, jt, 2);               // slice 2 overlaps MFMA of slice 1
      MFMAQ(aRb, 1);
      ISSUE_A(aRb, jt, 3);               // slice 3 overlaps MFMA of slice 2
      MFMAQ(aRa, 2);
      MFMAQ(aRb, 3);
      GATES(jt);
    }
  }
  __syncthreads();                       // final state (h_s[0]) committed

  // ---- export final h (unswizzled) to hstate[b][dir][40][256] ----
  #pragma unroll
  for (int pass = 0; pass < 5; ++pass) {
    int row = 8*pass + (tid >> 5);
    int c0  = (tid & 31) * 8;
    half8 v = *(const half8*)&h_s[0][row][c0 ^ ((row & 7) << 3)];
    *(half8*)&hstate[(((size_t)b*2 + dir)*40 + row)*256 + c0] = v;
  }
}

// ---------------- K3: dense + attention head, 1 block = 1 card ----------------
__global__ __launch_bounds__(256) void k3_head(
    const float* __restrict__ bd, const float* __restrict__ att,
    const _Float16* __restrict__ hstate, const _Float16* __restrict__ wdt,
    float* __restrict__ out)
{
  __shared__ _Float16 d_s[256][56];
  __shared__ float att_s[256];
  __shared__ float sc_s[40];
  __shared__ float wgt[40];

  const int b   = blockIdx.x;
  const int tid = threadIdx.x;
  const int wv  = tid >> 6;
  const int ln  = tid & 63;
  const int l16 = ln & 15;
  const int lq  = ln >> 4;

  att_s[tid] = att[tid];

  int pD2[3];
  #pragma unroll
  for (int nt=0;nt<3;++nt){ int p = 16*nt + l16; pD2[nt] = (p < 40) ? p : 39; }
  const _Float16* hb = hstate + (size_t)b*2*40*256;

  f32x4 dacc[4][3];
  #pragma unroll
  for (int ml=0;ml<4;++ml)
    #pragma unroll
    for (int nt=0;nt<3;++nt){ f32x4 z0; z0[0]=0.f;z0[1]=0.f;z0[2]=0.f;z0[3]=0.f; dacc[ml][nt]=z0; }

  #pragma unroll
  for (int kq = 0; kq < 8; ++kq) {        // k slices of 64: 0..3 fw state, 4..7 bw state
    half8 adA[4], adB[4];
    #pragma unroll
    for (int ml=0;ml<4;++ml) {
      const _Float16* wp = wdt + (size_t)(16*(4*wv+ml)+l16)*512 + 64*kq + 8*lq;
      adA[ml] = *(const half8*)(wp);
      adB[ml] = *(const half8*)(wp + 32);
    }
    #pragma unroll
    for (int kk2=0;kk2<2;++kk2) {
      half8 bD[3];
      #pragma unroll
      for (int nt=0;nt<3;++nt)
        bD[nt] = *(const half8*)(hb + ((size_t)(kq>>2)*40 + pD2[nt])*256
                                    + 64*(kq&3) + 32*kk2 + 8*lq);
      #pragma unroll
      for (int ml=0;ml<4;++ml) {
        half8 a0 = kk2 ? adB[ml] : adA[ml];
        #pragma unroll
        for (int nt=0;nt<3;++nt) dacc[ml][nt] = MFMA16(a0, bD[nt], dacc[ml][nt]);
      }
    }
  }
  #pragma unroll
  for (int ml = 0; ml < 4; ++ml) {
    int d0 = 16*(4*wv+ml) + 4*lq;
    float4 bv = *(const float4*)&bd[d0];
    float bvr[4] = {bv.x, bv.y, bv.z, bv.w};
    #pragma unroll
    for (int nt = 0; nt < 3; ++nt) {
      int p = 16*nt + l16;
      #pragma unroll
      for (int r = 0; r < 4; ++r) {
        float val = tanhn_(dacc[ml][nt][r] + bvr[r]);
        d_s[d0 + r][p] = (_Float16)val;
      }
    }
  }
  __syncthreads();
  // ---------- attention: 10 path-scores per wave, softmax, weighted sum ----------
  #pragma unroll
  for (int q = 0; q < 10; ++q) {
    int pp = 10*wv + q;
    float s = 0.0f;
    #pragma unroll
    for (int j = 0; j < 4; ++j) {
      int d = 64*j + ln;
      s += (float)d_s[d][pp] * att_s[d];
    }
    #pragma unroll
    for (int off = 32; off > 0; off >>= 1) s += __shfl_xor(s, off);
    if (ln == 0) sc_s[pp] = s;
  }
  __syncthreads();
  if (wv == 0) {
    float sc = (ln < 40) ? sc_s[ln] : -1e30f;
    float m = sc;
    #pragma unroll
    for (int off = 32; off > 0; off >>= 1) m = fmaxf(m, __shfl_xor(m, off));
    float e = __expf(sc - m);
    float se = e;
    #pragma unroll
    for (int off = 32; off > 0; off >>= 1) se += __shfl_xor(se, off);
    if (ln < 40) wgt[ln] = e / se;
  }
  __syncthreads();
  {
    float o = 0.0f;
    #pragma unroll 8
    for (int p = 0; p < 40; ++p) o += wgt[p] * (float)d_s[tid][p];
    out[b*256 + tid] = o;
  }
}

extern "C" void kernel_launch(void* const* d_in, const int* in_sizes, int n_in,
                              void* d_out, int out_size, void* d_ws, size_t ws_size,
                              hipStream_t stream)
{
  (void)in_sizes; (void)n_in; (void)out_size;
  const int*   x   = (const int*)  d_in[0];
  const float* emb = (const float*)d_in[1];
  const float* Wk  = (const float*)d_in[2];
  const float* Wr  = (const float*)d_in[3];
  const float* bi  = (const float*)d_in[4];
  const float* Wd  = (const float*)d_in[5];
  const float* bd  = (const float*)d_in[6];
  const float* att = (const float*)d_in[7];
  float* out = (float*)d_out;

  if (ws_size < 52887552u) return;   // need 52.9 MB scratch
  char* ws = (char*)d_ws;
  _Float16* embw   = (_Float16*)(ws + 0);          // [20000][1024] fp16 = 40,960,000 B
  _Float16* wrtb   = (_Float16*)(ws + 40960000);   // [4][256][256] fp16 =    524,288 B
  _Float16* wkt    = (_Float16*)(ws + 41484288);   // [1024][320]   fp16 =    655,360 B
  _Float16* wdt    = (_Float16*)(ws + 42139648);   // [256][512]    fp16 =    262,144 B
  _Float16* hstate = (_Float16*)(ws + 42401792);   // [256][2][40][256] fp16 = 10,485,760 B

  k0_prep<<<dim3(1280), dim3(256), 0, stream>>>(Wk, Wr, Wd, wkt, wrtb, wdt);
  k1_embw<<<dim3(313), dim3(512), 0, stream>>>(emb, bi, wkt, embw);
  k2_rnn <<<dim3(512), dim3(256), 0, stream>>>(x, embw, wrtb, hstate);
  k3_head<<<dim3(256), dim3(256), 0, stream>>>(bd, att, hstate, wdt, out);
}

// Round 12
// 614.806 us; speedup vs baseline: 1.1928x; 1.0172x over previous
//
#include <hip/hip_runtime.h>

using half8  = __attribute__((ext_vector_type(8))) _Float16;
using half4v = __attribute__((ext_vector_type(4))) _Float16;
using f32x4  = __attribute__((ext_vector_type(4))) float;

#define MFMA16(a,b,c) __builtin_amdgcn_mfma_f32_16x16x32_f16((a),(b),(c),0,0,0)
#define LOG2E 1.4426950408889634f
#define KTC  -2.8853900817779268f   /* -2*log2(e): tanh(c) = 2/(1+2^(c*KTC)) - 1 */

__device__ __forceinline__ float sigp_(float zp){           // sigmoid, zp pre-scaled by log2e
  return __builtin_amdgcn_rcpf(1.0f + exp2f(-zp));
}
__device__ __forceinline__ float tanhp_(float zp){          // tanh, zp pre-scaled by log2e
  return fmaf(2.0f, __builtin_amdgcn_rcpf(1.0f + exp2f(-2.0f*zp)), -1.0f);
}
__device__ __forceinline__ float tanhn_(float x){           // tanh, natural units
  return fmaf(2.0f, __builtin_amdgcn_rcpf(1.0f + exp2f(x*KTC)), -1.0f);
}

// ---------------- K0: weight transposes / fp16 packing ----------------
// wkt, wrtb carry a baked log2(e) factor so gates use raw exp2.
// wrtb linear: [4 jt][256 r][256 k], r = 64*gate + i  <-> g = 256*gate + 64*jt + i
__global__ void k0_prep(const float* __restrict__ Wk, const float* __restrict__ Wr,
                        const float* __restrict__ Wd, _Float16* __restrict__ wkt,
                        _Float16* __restrict__ wrtb, _Float16* __restrict__ wdt)
{
  int i = blockIdx.x * 256 + threadIdx.x;
  if (i < 1024*320) {
    int g = i / 320, k = i - g*320;
    wkt[i] = (_Float16)((k < 300) ? Wk[k*1024 + g]*LOG2E : 0.0f);
  }
  if (i < 4*256*256) {
    int jt = i >> 16, r = (i >> 8) & 255, k = i & 255;
    int g = ((r >> 6) << 8) + (jt << 6) + (r & 63);
    wrtb[i] = (_Float16)(Wr[k*1024 + g]*LOG2E);
  }
  if (i < 256*512) {
    int d = i >> 9, k = i & 511;
    wdt[i] = (_Float16)Wd[k*256 + d];
  }
}

// ---------------- K1: embW = (emb @ Wk + b)*log2e -> embw[v][1024] ----------------
__global__ __launch_bounds__(512, 2) void k1_embw(
    const float* __restrict__ emb, const float* __restrict__ bias,
    const _Float16* __restrict__ wkt, _Float16* __restrict__ embw)
{
  __shared__ _Float16 a_s[1024][40];
  __shared__ _Float16 e_s[64][40];
  const int tid = threadIdx.x;
  const int wv = tid >> 6, ln = tid & 63, l16 = ln & 15, lq = ln >> 4;
  const int v0 = blockIdx.x * 64;

  f32x4 acc[8][4];
  #pragma unroll
  for (int ml=0;ml<8;++ml)
    #pragma unroll
    for (int nt=0;nt<4;++nt){ f32x4 z0; z0[0]=0.f;z0[1]=0.f;z0[2]=0.f;z0[3]=0.f; acc[ml][nt]=z0; }

  const int evv = tid >> 2;
  const int ekq = tid & 3;

  for (int c = 0; c < 10; ++c) {
    {
      const uint4* sp  = (const uint4*)(wkt + (size_t)(2*tid)*320 + 32*c);
      uint4 r0=sp[0], r1=sp[1], r2=sp[2], r3=sp[3];
      const uint4* sp2 = (const uint4*)(wkt + (size_t)(2*tid+1)*320 + 32*c);
      uint4 r4=sp2[0], r5=sp2[1], r6=sp2[2], r7=sp2[3];
      uint4* dq  = (uint4*)&a_s[2*tid][0];
      dq[0]=r0; dq[1]=r1; dq[2]=r2; dq[3]=r3;
      uint4* dq2 = (uint4*)&a_s[2*tid+1][0];
      dq2[0]=r4; dq2[1]=r5; dq2[2]=r6; dq2[3]=r7;
    }
    if (tid < 256) {
      int vsrc = v0 + evv; if (vsrc > 19999) vsrc = 19999;
      float f0,f1,f2,f3,f4,f5,f6,f7;
      if (c < 9) {
        const float4* sp = (const float4*)(emb + (size_t)vsrc*300 + 32*c + 8*ekq);
        float4 fa = sp[0], fb = sp[1];
        f0=fa.x; f1=fa.y; f2=fa.z; f3=fa.w; f4=fb.x; f5=fb.y; f6=fb.z; f7=fb.w;
      } else {
        const float* sp = emb + (size_t)vsrc*300;
        int k0 = 288 + 8*ekq;
        f0 = (k0+0<300)? sp[k0+0] : 0.f;  f1 = (k0+1<300)? sp[k0+1] : 0.f;
        f2 = (k0+2<300)? sp[k0+2] : 0.f;  f3 = (k0+3<300)? sp[k0+3] : 0.f;
        f4 = (k0+4<300)? sp[k0+4] : 0.f;  f5 = (k0+5<300)? sp[k0+5] : 0.f;
        f6 = (k0+6<300)? sp[k0+6] : 0.f;  f7 = (k0+7<300)? sp[k0+7] : 0.f;
      }
      half8 hv;
      hv[0]=(_Float16)f0; hv[1]=(_Float16)f1; hv[2]=(_Float16)f2; hv[3]=(_Float16)f3;
      hv[4]=(_Float16)f4; hv[5]=(_Float16)f5; hv[6]=(_Float16)f6; hv[7]=(_Float16)f7;
      *(half8*)&e_s[evv][8*ekq] = hv;
    }
    __syncthreads();
    half8 bf[4];
    #pragma unroll
    for (int nt=0;nt<4;++nt) bf[nt] = *(const half8*)&e_s[16*nt + l16][8*lq];
    #pragma unroll
    for (int ml=0;ml<8;++ml) {
      half8 af = *(const half8*)&a_s[16*(8*wv+ml) + l16][8*lq];
      #pragma unroll
      for (int nt=0;nt<4;++nt) acc[ml][nt] = MFMA16(af, bf[nt], acc[ml][nt]);
    }
    __syncthreads();
  }
  #pragma unroll
  for (int ml=0;ml<8;++ml) {
    int g0 = 16*(8*wv+ml) + 4*lq;
    float4 bv = *(const float4*)&bias[g0];
    float bvr[4] = {bv.x*LOG2E, bv.y*LOG2E, bv.z*LOG2E, bv.w*LOG2E};
    int jt = (g0 >> 6) & 3;
    int c0 = ((g0 >> 8) << 6) + (g0 & 63);
    #pragma unroll
    for (int nt=0;nt<4;++nt) {
      int v = v0 + 16*nt + l16;
      if (v < 20000) {
        half4v hv;
        hv[0]=(_Float16)(acc[ml][nt][0]+bvr[0]);
        hv[1]=(_Float16)(acc[ml][nt][1]+bvr[1]);
        hv[2]=(_Float16)(acc[ml][nt][2]+bvr[2]);
        hv[3]=(_Float16)(acc[ml][nt][3]+bvr[3]);
        *(half4v*)&embw[(size_t)v*1024 + 256*jt + c0] = hv;
      }
    }
  }
}

// ---------------- K2: bi-LSTM recurrence, 1 block = (card, direction) ----------------
// R12 change (vs R11): cell state back to REGISTERS with four statically-named arrays
// (cA/cB/cC/cD) selected by a wave-uniform jt branch chain -> no dynamic register
// indexing (rule #20), jt stays a real loop (bounded scheduling regions, no R9-style
// live-range spill). This deletes c_s from LDS: 97.9KB -> 48KB -> TWO blocks/CU
// (2 waves/SIMD from independent blocks, no barrier coupling; all 512 blocks resident
// in one round instead of two). __launch_bounds__(256,2) caps regs at 256/wave
// (demand ~205 = R11's 156 + 48 c-regs) so the 2-blocks/CU occupancy is guaranteed.

#define NEXT_IDXC(T) do { int tt_ = dtt0 + dsgn*(T); \
    _Pragma("unroll") for (int nt=0;nt<3;++nt) \
      idxc[nt] = x[xb + pA[nt]*12 + tt_]; \
  } while(0)

#define ISSUE_E(JT) do { \
    _Pragma("unroll") for (int nt=0;nt<3;++nt) { \
      const _Float16* ep = embw + (size_t)idxc[nt]*1024 + 256*(JT) + ebase; \
      _Pragma("unroll") for (int g=0;g<4;++g) eR[g][nt] = *(const half4v*)(ep + 64*g); \
    } } while(0)

#define ACC_FROM_E() do { \
    _Pragma("unroll") for (int g=0;g<4;++g) \
      _Pragma("unroll") for (int nt=0;nt<3;++nt) { \
        f32x4 a0; a0[0]=(float)eR[g][nt][0]; a0[1]=(float)eR[g][nt][1]; \
        a0[2]=(float)eR[g][nt][2]; a0[3]=(float)eR[g][nt][3]; acc[g][nt]=a0; \
      } } while(0)

#define ISSUE_A(BUF,JT,KQ) do { \
    const _Float16* ap = wrtb + abase + 65536*(JT) + 64*(KQ); \
    _Pragma("unroll") for (int g=0;g<4;++g) { \
      BUF[2*g+0] = *(const half8*)(ap + 16384*g); \
      BUF[2*g+1] = *(const half8*)(ap + 16384*g + 32); \
    } } while(0)

#define MFMAQ(BUF,KQ) do { \
    _Pragma("unroll") for (int kk2=0;kk2<2;++kk2) { \
      half8 bF[3]; \
      _Pragma("unroll") for (int nt=0;nt<3;++nt) \
        bF[nt] = *(const half8*)(hc + bbase[nt] + ((64*(KQ)+32*kk2+8*lq) ^ bswz[nt])); \
      _Pragma("unroll") for (int g=0;g<4;++g) \
        _Pragma("unroll") for (int nt=0;nt<3;++nt) \
          acc[g][nt] = MFMA16(BUF[2*g+kk2], bF[nt], acc[g][nt]); \
    } } while(0)

#define GATES_J(JT, CR) do { \
    _Pragma("unroll") for (int nt=0;nt<3;++nt) { \
      f32x4 cn_; half4v hv; \
      _Pragma("unroll") for (int r=0;r<4;++r) { \
        float zi=acc[0][nt][r], zf=acc[1][nt][r], zg=acc[2][nt][r], zo=acc[3][nt][r]; \
        float cn = fmaf(sigp_(zf), CR[nt][r], sigp_(zi)*tanhp_(zg)); \
        cn_[r]=cn; hv[r]=(_Float16)(sigp_(zo)*tanhn_(cn)); \
      } \
      CR[nt] = cn_; \
      *(half4v*)(hn + bbase[nt] + ((64*(JT)+16*hq+4*lq) ^ bswz[nt])) = hv; \
    } } while(0)

#define GATES0_J(JT, CR) do { \
    _Pragma("unroll") for (int nt=0;nt<3;++nt) { \
      f32x4 cn_; half4v hv; \
      _Pragma("unroll") for (int r=0;r<4;++r) { \
        float zi=acc[0][nt][r], zg=acc[2][nt][r], zo=acc[3][nt][r]; \
        float cn = sigp_(zi)*tanhp_(zg); \
        cn_[r]=cn; hv[r]=(_Float16)(sigp_(zo)*tanhn_(cn)); \
      } \
      CR[nt] = cn_; \
      *(half4v*)(hn + bbase[nt] + ((64*(JT)+16*hq+4*lq) ^ bswz[nt])) = hv; \
    } } while(0)

__global__ __launch_bounds__(256, 2) void k2_rnn(
    const int* __restrict__ x, const _Float16* __restrict__ embw,
    const _Float16* __restrict__ wrtb, _Float16* __restrict__ hstate)
{
  __shared__ _Float16 h_s[2][48][256];   // 48 KB total -> 2 blocks/CU

  const int bid = blockIdx.x;
  const int b   = bid & 255;             // card
  const int dir = bid >> 8;              // 0 = fw, 1 = bw (block-uniform)
  const int tid = threadIdx.x;
  const int wv  = tid >> 6;
  const int ln  = tid & 63;
  const int l16 = ln & 15;
  const int lq  = ln >> 4;
  const int hq  = wv;                    // 16-col subtile in each 64-col gate chunk

  const int dtt0 = dir ? 11 : 0;
  const int dsgn = dir ? -1 : 1;

  int pA[3], bbase[3], bswz[3];
  #pragma unroll
  for (int nt=0;nt<3;++nt) {
    int s = 16*nt + l16;                 // seq row 0..47 (40..47 dup path 39)
    pA[nt] = (s < 40) ? s : 39;
    bbase[nt] = s*256; bswz[nt] = (s&7)<<3;
  }
  const int xb = b*480;
  const int ebase = 16*hq + 4*lq;
  const size_t abase = (size_t)(16*hq + l16)*256 + 8*lq;

  half4v eR[4][3];
  half8  aRa[8], aRb[8];
  f32x4  acc[4][3];
  f32x4  cA[3], cB[3], cC[3], cD[3];     // cell state, statically-named per jt chunk
  int idxc[3];

  NEXT_IDXC(0);
  ISSUE_E(0);

  // ---- t = 0: z = xg (h=0, no MFMA); fully unrolled so c-writes are static ----
  {
    _Float16* hn = &h_s[1][0][0];
    #pragma unroll
    for (int jt = 0; jt < 4; ++jt) {
      ACC_FROM_E();
      if (jt < 3) { ISSUE_E(jt+1); }
      else        { NEXT_IDXC(1); ISSUE_E(0); }
      if      (jt == 0) GATES0_J(0, cA);
      else if (jt == 1) GATES0_J(1, cB);
      else if (jt == 2) GATES0_J(2, cC);
      else              GATES0_J(3, cD);
    }
  }

  // ---- t = 1..11: 4 jt chunks/step, 2-slice A rotation inside each ----
  #pragma unroll 1
  for (int t = 1; t < 12; ++t) {
    __syncthreads();                     // h[t&1] committed by all waves
    const _Float16* hc = &h_s[t&1][0][0];
    _Float16*       hn = &h_s[(t+1)&1][0][0];
    const bool last = (t == 11);
    #pragma unroll 1
    for (int jt = 0; jt < 4; ++jt) {
      ISSUE_A(aRa, jt, 0);               // slices 0,1 in flight
      ISSUE_A(aRb, jt, 1);
      ACC_FROM_E();
      if (jt < 3)      { ISSUE_E(jt+1); }
      else if (!last)  { NEXT_IDXC(t+1); ISSUE_E(0); }
      MFMAQ(aRa, 0);
      ISSUE_A(aRa, jt, 2);               // slice 2 overlaps MFMA of slice 1
      MFMAQ(aRb, 1);
      ISSUE_A(aRb, jt, 3);               // slice 3 overlaps MFMA of slice 2
      MFMAQ(aRa, 2);
      MFMAQ(aRb, 3);
      if      (jt == 0) GATES_J(0, cA);  // wave-uniform branch: static c names
      else if (jt == 1) GATES_J(1, cB);
      else if (jt == 2) GATES_J(2, cC);
      else              GATES_J(3, cD);
    }
  }
  __syncthreads();                       // final state (h_s[0]) committed

  // ---- export final h (unswizzled) to hstate[b][dir][40][256] ----
  #pragma unroll
  for (int pass = 0; pass < 5; ++pass) {
    int row = 8*pass + (tid >> 5);
    int c0  = (tid & 31) * 8;
    half8 v = *(const half8*)&h_s[0][row][c0 ^ ((row & 7) << 3)];
    *(half8*)&hstate[(((size_t)b*2 + dir)*40 + row)*256 + c0] = v;
  }
}

// ---------------- K3: dense + attention head, 1 block = 1 card ----------------
__global__ __launch_bounds__(256) void k3_head(
    const float* __restrict__ bd, const float* __restrict__ att,
    const _Float16* __restrict__ hstate, const _Float16* __restrict__ wdt,
    float* __restrict__ out)
{
  __shared__ _Float16 d_s[256][56];
  __shared__ float att_s[256];
  __shared__ float sc_s[40];
  __shared__ float wgt[40];

  const int b   = blockIdx.x;
  const int tid = threadIdx.x;
  const int wv  = tid >> 6;
  const int ln  = tid & 63;
  const int l16 = ln & 15;
  const int lq  = ln >> 4;

  att_s[tid] = att[tid];

  int pD2[3];
  #pragma unroll
  for (int nt=0;nt<3;++nt){ int p = 16*nt + l16; pD2[nt] = (p < 40) ? p : 39; }
  const _Float16* hb = hstate + (size_t)b*2*40*256;

  f32x4 dacc[4][3];
  #pragma unroll
  for (int ml=0;ml<4;++ml)
    #pragma unroll
    for (int nt=0;nt<3;++nt){ f32x4 z0; z0[0]=0.f;z0[1]=0.f;z0[2]=0.f;z0[3]=0.f; dacc[ml][nt]=z0; }

  #pragma unroll
  for (int kq = 0; kq < 8; ++kq) {        // k slices of 64: 0..3 fw state, 4..7 bw state
    half8 adA[4], adB[4];
    #pragma unroll
    for (int ml=0;ml<4;++ml) {
      const _Float16* wp = wdt + (size_t)(16*(4*wv+ml)+l16)*512 + 64*kq + 8*lq;
      adA[ml] = *(const half8*)(wp);
      adB[ml] = *(const half8*)(wp + 32);
    }
    #pragma unroll
    for (int kk2=0;kk2<2;++kk2) {
      half8 bD[3];
      #pragma unroll
      for (int nt=0;nt<3;++nt)
        bD[nt] = *(const half8*)(hb + ((size_t)(kq>>2)*40 + pD2[nt])*256
                                    + 64*(kq&3) + 32*kk2 + 8*lq);
      #pragma unroll
      for (int ml=0;ml<4;++ml) {
        half8 a0 = kk2 ? adB[ml] : adA[ml];
        #pragma unroll
        for (int nt=0;nt<3;++nt) dacc[ml][nt] = MFMA16(a0, bD[nt], dacc[ml][nt]);
      }
    }
  }
  #pragma unroll
  for (int ml = 0; ml < 4; ++ml) {
    int d0 = 16*(4*wv+ml) + 4*lq;
    float4 bv = *(const float4*)&bd[d0];
    float bvr[4] = {bv.x, bv.y, bv.z, bv.w};
    #pragma unroll
    for (int nt = 0; nt < 3; ++nt) {
      int p = 16*nt + l16;
      #pragma unroll
      for (int r = 0; r < 4; ++r) {
        float val = tanhn_(dacc[ml][nt][r] + bvr[r]);
        d_s[d0 + r][p] = (_Float16)val;
      }
    }
  }
  __syncthreads();
  // ---------- attention: 10 path-scores per wave, softmax, weighted sum ----------
  #pragma unroll
  for (int q = 0; q < 10; ++q) {
    int pp = 10*wv + q;
    float s = 0.0f;
    #pragma unroll
    for (int j = 0; j < 4; ++j) {
      int d = 64*j + ln;
      s += (float)d_s[d][pp] * att_s[d];
    }
    #pragma unroll
    for (int off = 32; off > 0; off >>= 1) s += __shfl_xor(s, off);
    if (ln == 0) sc_s[pp] = s;
  }
  __syncthreads();
  if (wv == 0) {
    float sc = (ln < 40) ? sc_s[ln] : -1e30f;
    float m = sc;
    #pragma unroll
    for (int off = 32; off > 0; off >>= 1) m = fmaxf(m, __shfl_xor(m, off));
    float e = __expf(sc - m);
    float se = e;
    #pragma unroll
    for (int off = 32; off > 0; off >>= 1) se += __shfl_xor(se, off);
    if (ln < 40) wgt[ln] = e / se;
  }
  __syncthreads();
  {
    float o = 0.0f;
    #pragma unroll 8
    for (int p = 0; p < 40; ++p) o += wgt[p] * (float)d_s[tid][p];
    out[b*256 + tid] = o;
  }
}

extern "C" void kernel_launch(void* const* d_in, const int* in_sizes, int n_in,
                              void* d_out, int out_size, void* d_ws, size_t ws_size,
                              hipStream_t stream)
{
  (void)in_sizes; (void)n_in; (void)out_size;
  const int*   x   = (const int*)  d_in[0];
  const float* emb = (const float*)d_in[1];
  const float* Wk  = (const float*)d_in[2];
  const float* Wr  = (const float*)d_in[3];
  const float* bi  = (const float*)d_in[4];
  const float* Wd  = (const float*)d_in[5];
  const float* bd  = (const float*)d_in[6];
  const float* att = (const float*)d_in[7];
  float* out = (float*)d_out;

  if (ws_size < 52887552u) return;   // need 52.9 MB scratch
  char* ws = (char*)d_ws;
  _Float16* embw   = (_Float16*)(ws + 0);          // [20000][1024] fp16 = 40,960,000 B
  _Float16* wrtb   = (_Float16*)(ws + 40960000);   // [4][256][256] fp16 =    524,288 B
  _Float16* wkt    = (_Float16*)(ws + 41484288);   // [1024][320]   fp16 =    655,360 B
  _Float16* wdt    = (_Float16*)(ws + 42139648);   // [256][512]    fp16 =    262,144 B
  _Float16* hstate = (_Float16*)(ws + 42401792);   // [256][2][40][256] fp16 = 10,485,760 B

  k0_prep<<<dim3(1280), dim3(256), 0, stream>>>(Wk, Wr, Wd, wkt, wrtb, wdt);
  k1_embw<<<dim3(313), dim3(512), 0, stream>>>(emb, bi, wkt, embw);
  k2_rnn <<<dim3(512), dim3(256), 0, stream>>>(x, embw, wrtb, hstate);
  k3_head<<<dim3(256), dim3(256), 0, stream>>>(bd, att, hstate, wdt, out);
}